// Round 11
// baseline (115.239 us; speedup 1.0000x reference)
//
#include <hip/hip_runtime.h>
#include <hip/hip_bf16.h>

// TripletLoss batch-hard mining, B=8192, D=256.
// R12: R11 (symmetric tile-pair Gram, 256-thr blocks, lb(256,3), atomic-free
//      slot stores) with the MFMA shape switched 16x16x32 -> 32x32x16:
//      half the MFMA instructions, +25% matrix-pipe FLOP/cyc (m119), half
//      the inner-loop iterations. A/B operand layout = [row/col=lane&31]
//      [k=(lane>>5)*8+e] (generalization of the verified 16x16 pattern);
//      C/D = col=lane&31, row=(reg&3)+8*(reg>>2)+4*(lane>>5) (m74/m101).
//      Geometry, staging discipline, mining key, slot convention unchanged.

constexpr int NB = 8192;
constexpr int ND = 256;
constexpr int TI = 128;               // rows per tile (4 waves x 32 rows)
constexpr int BJ = 64;                // cols staged per iteration
constexpr int NT = NB / TI;           // 64 tiles per side
constexpr int NPAIR = NT * (NT + 1) / 2;  // 2080 blocks
constexpr int NITER = TI / BJ;        // 2

typedef __attribute__((ext_vector_type(8))) short bf16x8;
typedef __attribute__((ext_vector_type(16))) float f32x16;

typedef __attribute__((address_space(3))) unsigned int lds_u32;
typedef __attribute__((address_space(1))) const unsigned int g_u32;

__device__ inline void load_lds16(const unsigned short* g, unsigned short* l) {
    __builtin_amdgcn_global_load_lds((g_u32*)g, (lds_u32*)l, 16, 0, 0);
}

__device__ inline unsigned short f2bf(float v) {
    __hip_bfloat16 b = __float2bfloat16(v);
    return *reinterpret_cast<unsigned short*>(&b);
}

// ---------------- Kernel 1: normalize rows -> bf16, CHUNK-MAJOR ------------
__global__ __launch_bounds__(256) void norm_kernel(const float* __restrict__ X,
                                                   unsigned short* __restrict__ Xbt,
                                                   float* accum, int* done) {
    const int t = threadIdx.x;
    const int rb = blockIdx.x * 32;
    const int r = t >> 3, e = t & 7;
    if (blockIdx.x == 0 && t == 0) { accum[0] = 0.f; accum[1] = 0.f; *done = 0; }

    const float4* src = (const float4*)(X + (size_t)(rb + r) * ND + e * 32);
    float4 v[8];
    #pragma unroll
    for (int k = 0; k < 8; k++) v[k] = src[k];

    float s = 0.f;
    #pragma unroll
    for (int k = 0; k < 8; k++) {
        s += v[k].x * v[k].x; s += v[k].y * v[k].y;
        s += v[k].z * v[k].z; s += v[k].w * v[k].w;
    }
    #pragma unroll
    for (int m = 1; m <= 4; m <<= 1) s += __shfl_xor(s, m, 64);
    const float sc = 1.0f / fmaxf(sqrtf(s), 1e-12f);

    #pragma unroll
    for (int k = 0; k < 4; k++) {
        const float* f = (const float*)&v[2 * k];
        unsigned short tmp[8];
        #pragma unroll
        for (int q = 0; q < 8; q++) tmp[q] = f2bf(f[q] * sc);
        *(bf16x8*)(Xbt + ((size_t)(e * 4 + k) * NB + rb + r) * 8) = *(bf16x8*)tmp;
    }
}

// ---------------- Kernel 2: symmetric Gram + two-direction hard mining ------
// Block = tile-pair (ti<=tj). 4 waves x 32 rows of ti in registers (A-frags
// for mfma_32x32x16: afrag[ks] = row (rowbase+lane&31), chunk (2ks+lane>>5)).
// B: BJ=64 cols of tj staged in LDS as 32 x 1KB regions; region r holds, at
// slot L: B[col=(r&1)*32+(L&31)][chunk=2*(r>>1)+(L>>5)] -> the (cb,ks) read
// region ks*2+cb is lane-sequential (conflict-free ds_read_b128).
// Mining key: key = s + 8*(lrow!=lcol); symmetric. Slot convention as R11:
// row-dir -> slot tj, col-dir -> slot ti; diagonal writes bitwise-identical
// values twice (benign, proven R8-R11).
__global__ __launch_bounds__(256, 3) void mine_kernel(
    const unsigned short* __restrict__ Xbt, const int* __restrict__ labels,
    float* __restrict__ posP, float* __restrict__ negP) {
    __shared__ __align__(16) unsigned short Bt[32 * 512];  // 32 KB single buf
    __shared__ int Lall[TI];                               // tj's 128 labels
    __shared__ float colMn[4][BJ], colMx[4][BJ];           // per-wave col partials

    const int tid = threadIdx.x;
    const int w = tid >> 6;           // 0..3
    const int lane = tid & 63;
    const int hi = lane >> 5;         // 0/1
    const int l32 = lane & 31;

    // triangular decode: blockIdx.x -> (ti, tj), ti <= tj
    int ti = 0, rem = blockIdx.x;
    while (rem >= NT - ti) { rem -= NT - ti; ti++; }
    const int tj = ti + rem;

    const int rowbase = ti * TI + w * 32;
    const int jstart = tj * TI;

    if (tid < TI) Lall[tid] = labels[jstart + tid];

    // A fragments: afrag[ks] = 16B of row (rowbase+l32), chunk (2*ks+hi)
    // => lane provides A[row=l32][k = ks*16 + hi*8 + e]
    bf16x8 afrag[16];
    #pragma unroll
    for (int ks = 0; ks < 16; ks++) {
        const size_t u = (size_t)(2 * ks + hi) * NB + (rowbase + l32);
        afrag[ks] = *(const bf16x8*)(Xbt + u * 8);
    }

    // row labels packed 4x8-bit per reg-group g: byte b of lpack[g] =
    // label[rowbase + b + 8*g + 4*hi]  (C row for reg = (reg&3)+8*(reg>>2)+4*hi)
    unsigned int lpack[4];
    #pragma unroll
    for (int g = 0; g < 4; g++) {
        unsigned int p = 0;
        #pragma unroll
        for (int b = 0; b < 4; b++)
            p |= ((unsigned int)labels[rowbase + b + 8 * g + 4 * hi] & 0xffu)
                 << (8 * b);
        lpack[g] = p;
    }

    float minK[16], maxK[16];
    #pragma unroll
    for (int r = 0; r < 16; r++) { minK[r] = 1e30f; maxK[r] = -1e30f; }

    auto stage = [&](int jt) {
        const int jbase = jstart + jt * BJ;
        #pragma unroll
        for (int s = 0; s < 8; s++) {
            const int rg = w * 8 + s;                 // 32 regions over 4 waves
            const size_t u = (size_t)(2 * (rg >> 1) + hi) * NB
                             + (jbase + (rg & 1) * 32 + l32);
            load_lds16(Xbt + u * 8, Bt + rg * 512);
        }
    };

    stage(0);
    __syncthreads();   // vmcnt drained: Bt(0) + Lall ready

    #pragma unroll 1
    for (int jt = 0; jt < NITER; jt++) {
        #pragma unroll
        for (int cb = 0; cb < 2; cb++) {
            const int flc = Lall[jt * BJ + cb * 32 + l32];
            f32x16 acc = {};
            #pragma unroll
            for (int ks = 0; ks < 16; ks++) {
                const bf16x8 b = *(const bf16x8*)(Bt + (ks * 2 + cb) * 512 + lane * 8);
                acc = __builtin_amdgcn_mfma_f32_32x32x16_bf16(afrag[ks], b, acc,
                                                              0, 0, 0);
            }
            float cP = 1e30f, cN = -1e30f;
            #pragma unroll
            for (int reg = 0; reg < 16; reg++) {
                const int lr = (int)((lpack[reg >> 2] >> (8 * (reg & 3))) & 0xffu);
                const float key = acc[reg] + ((lr != flc) ? 8.0f : 0.0f);
                minK[reg] = fminf(minK[reg], key);   // row-direction
                maxK[reg] = fmaxf(maxK[reg], key);
                cP = fminf(cP, key);                 // col-direction
                cN = fmaxf(cN, key);
            }
            // col-dir: combine the two row-halves (lane ^ 32 shares the col)
            cP = fminf(cP, __shfl_xor(cP, 32, 64));
            cN = fmaxf(cN, __shfl_xor(cN, 32, 64));
            if (hi == 0) {
                colMn[w][cb * 32 + l32] = cP;
                colMx[w][cb * 32 + l32] = cN;
            }
        }
        __syncthreads();            // Bt reads + colMn/colMx writes done
        if (jt + 1 < NITER) stage(jt + 1);
        // flush col-direction partials for this jt: PLAIN stores, slot ti
        if (tid < BJ) {
            float m = colMn[0][tid];
            #pragma unroll
            for (int ww = 1; ww < 4; ww++) m = fminf(m, colMn[ww][tid]);
            posP[(size_t)ti * NB + jstart + jt * BJ + tid] = m;
        } else if (tid < 2 * BJ) {
            const int c = tid - BJ;
            float M = colMx[0][c];
            #pragma unroll
            for (int ww = 1; ww < 4; ww++) M = fmaxf(M, colMx[ww][c]);
            negP[(size_t)ti * NB + jstart + jt * BJ + c] = M;
        }
        __syncthreads();            // staged Bt landed (vmcnt 0)
    }

    // row-direction: reduce over the 32 lanes sharing each row-half (bits 0..4);
    // PLAIN store into slot tj. Lanes 0 and 32 each store 16 rows (hi halves).
    #pragma unroll
    for (int reg = 0; reg < 16; reg++) {
        float p = minK[reg], n = maxK[reg];
        #pragma unroll
        for (int m = 1; m <= 16; m <<= 1) {
            p = fminf(p, __shfl_xor(p, m, 64));
            n = fmaxf(n, __shfl_xor(n, m, 64));
        }
        if (l32 == 0) {
            const int row = rowbase + (reg & 3) + 8 * (reg >> 2) + 4 * hi;
            posP[(size_t)tj * NB + row] = p;
            negP[(size_t)tj * NB + row] = n;
        }
    }
}

// ---------------- Kernel 3: reduce 64 slots, hinge, finalize ----------------
__global__ __launch_bounds__(256) void finish_kernel(
    const float* __restrict__ posP, const float* __restrict__ negP,
    float* accum, int* done, float* __restrict__ out) {
    const int i = blockIdx.x * 256 + threadIdx.x;
    float p = 1e30f, n = -1e30f;
    for (int u = 0; u < NT; u++) {
        p = fminf(p, posP[(size_t)u * NB + i]);
        n = fmaxf(n, negP[(size_t)u * NB + i]);
    }
    // p < 4: some positive existed; n > 4: some negative existed (key = s+8)
    const bool valid = (p < 4.0f) && (n > 4.0f);
    const float pos_d = fmaxf(1.0f - p, 0.0f);
    const float neg_d = fmaxf(1.0f - (n - 8.0f), 0.0f);
    float per = valid ? fmaxf(pos_d - neg_d + 1.0f, 0.0f) : 0.0f;
    float cnt = valid ? 1.0f : 0.0f;
    #pragma unroll
    for (int off = 32; off > 0; off >>= 1) {
        per += __shfl_down(per, off, 64);
        cnt += __shfl_down(cnt, off, 64);
    }
    __shared__ float sp[4], sc[4];
    const int wv = threadIdx.x >> 6, ln = threadIdx.x & 63;
    if (ln == 0) { sp[wv] = per; sc[wv] = cnt; }
    __syncthreads();
    if (threadIdx.x == 0) {
        atomicAdd(&accum[0], sp[0] + sp[1] + sp[2] + sp[3]);
        atomicAdd(&accum[1], sc[0] + sc[1] + sc[2] + sc[3]);
        __threadfence();
        const int old = atomicAdd(done, 1);
        if (old == (int)gridDim.x - 1) {
            const float s = __hip_atomic_load(&accum[0], __ATOMIC_RELAXED,
                                              __HIP_MEMORY_SCOPE_AGENT);
            const float c = __hip_atomic_load(&accum[1], __ATOMIC_RELAXED,
                                              __HIP_MEMORY_SCOPE_AGENT);
            out[0] = (c > 0.f) ? s / fmaxf(c, 1.f) : 0.f;
        }
    }
}

// ---------------- launcher --------------------------------------------------
extern "C" void kernel_launch(void* const* d_in, const int* in_sizes, int n_in,
                              void* d_out, int out_size, void* d_ws, size_t ws_size,
                              hipStream_t stream) {
    const float* X = (const float*)d_in[0];
    const int* labels = (const int*)d_in[1];
    float* out = (float*)d_out;

    char* ws = (char*)d_ws;
    unsigned short* Xbt = (unsigned short*)ws;                    // 4 MB
    float* posP = (float*)(ws + (size_t)4 * 1024 * 1024);         // 2 MB (64 x NB)
    float* negP = posP + (size_t)NT * NB;                         // 2 MB
    float* accum = negP + (size_t)NT * NB;                        // 8 B
    int* done = (int*)(accum + 2);                                // 4 B

    norm_kernel<<<NB / 32, 256, 0, stream>>>(X, Xbt, accum, done);
    mine_kernel<<<NPAIR, 256, 0, stream>>>(
        (const unsigned short*)Xbt, labels, posP, negP);
    finish_kernel<<<NB / 256, 256, 0, stream>>>(posP, negP, accum, done, out);
}

// Round 12
// 114.382 us; speedup vs baseline: 1.0075x; 1.0075x over previous
//
#include <hip/hip_runtime.h>
#include <hip/hip_bf16.h>

// TripletLoss batch-hard mining, B=8192, D=256.
// R13: strip-symmetric. R11's per-tile inner structure (16x16x32, afrag[2][8],
//      minK/maxK[2][4], lb(256,3) -- the ONE footprint proven not to spill)
//      kept byte-identical, but each block owns a strip of up to 4 tj-tiles:
//      544 blocks (all co-resident, single round), 4x setup amortization.
//      Slots: col-dir partial of col x (tile tj) from row-tile ti -> slot ti
//      (64 slots); row-dir partial of row y over strip s -> slot 64+s (<16).
//      finish reduces only the computable valid slot ranges (no init needed).

constexpr int NB = 8192;
constexpr int ND = 256;
constexpr int TI = 128;               // rows per tile (4 waves x 32 rows)
constexpr int BJ = 64;                // cols staged per iteration
constexpr int NT = NB / TI;           // 64 tiles per side
constexpr int SW = 4;                 // strip width (tiles)
// NBLK = sum over ti of ceil((NT-ti)/SW) = 544
constexpr int NBLK = 544;
constexpr int NSLOT = 80;             // 64 col-slots + 16 row-slots

typedef __attribute__((ext_vector_type(8))) short bf16x8;
typedef __attribute__((ext_vector_type(4))) float f32x4;

typedef __attribute__((address_space(3))) unsigned int lds_u32;
typedef __attribute__((address_space(1))) const unsigned int g_u32;

__device__ inline void load_lds16(const unsigned short* g, unsigned short* l) {
    __builtin_amdgcn_global_load_lds((g_u32*)g, (lds_u32*)l, 16, 0, 0);
}

__device__ inline unsigned short f2bf(float v) {
    __hip_bfloat16 b = __float2bfloat16(v);
    return *reinterpret_cast<unsigned short*>(&b);
}

// ---------------- Kernel 1: normalize rows -> bf16, CHUNK-MAJOR ------------
__global__ __launch_bounds__(256) void norm_kernel(const float* __restrict__ X,
                                                   unsigned short* __restrict__ Xbt,
                                                   float* accum, int* done) {
    const int t = threadIdx.x;
    const int rb = blockIdx.x * 32;
    const int r = t >> 3, e = t & 7;
    if (blockIdx.x == 0 && t == 0) { accum[0] = 0.f; accum[1] = 0.f; *done = 0; }

    const float4* src = (const float4*)(X + (size_t)(rb + r) * ND + e * 32);
    float4 v[8];
    #pragma unroll
    for (int k = 0; k < 8; k++) v[k] = src[k];

    float s = 0.f;
    #pragma unroll
    for (int k = 0; k < 8; k++) {
        s += v[k].x * v[k].x; s += v[k].y * v[k].y;
        s += v[k].z * v[k].z; s += v[k].w * v[k].w;
    }
    #pragma unroll
    for (int m = 1; m <= 4; m <<= 1) s += __shfl_xor(s, m, 64);
    const float sc = 1.0f / fmaxf(sqrtf(s), 1e-12f);

    #pragma unroll
    for (int k = 0; k < 4; k++) {
        const float* f = (const float*)&v[2 * k];
        unsigned short tmp[8];
        #pragma unroll
        for (int q = 0; q < 8; q++) tmp[q] = f2bf(f[q] * sc);
        *(bf16x8*)(Xbt + ((size_t)(e * 4 + k) * NB + rb + r) * 8) = *(bf16x8*)tmp;
    }
}

// ---------------- Kernel 2: strip-symmetric Gram + two-direction mining -----
// Block = (row-tile ti, strip s): rows ti*128..+128 in registers, cols
// tjs*128 .. tjs*128 + WT*128 staged 64 at a time (tjs = ti + 4s).
// LDS region rg = kc*4+nf holds, at lane L*16B:
//   B[col = nf*16 + (L&15)][kchunk = kc*4 + (L>>4)]  (lane-sequential reads).
// Mining key: key = s + 8*(lrow!=lcol); symmetric in (row,col).
__global__ __launch_bounds__(256, 3) void mine_kernel(
    const unsigned short* __restrict__ Xbt, const int* __restrict__ labels,
    float* __restrict__ posP, float* __restrict__ negP) {
    __shared__ __align__(16) unsigned short Bt[32 * 512];  // 32 KB single buf
    __shared__ int Lall[SW * TI];                          // strip labels (<=512)
    __shared__ float colMn[4][BJ], colMx[4][BJ];           // per-wave col partials

    const int tid = threadIdx.x;
    const int w = tid >> 6;           // 0..3
    const int lane = tid & 63;
    const int quad = lane >> 4;
    const int l16 = lane & 15;

    // decode blockIdx.x -> (ti, s): row tile + strip index
    int ti = 0, rem = blockIdx.x;
    int ns = (NT - ti + SW - 1) >> 2;
    while (rem >= ns) { rem -= ns; ti++; ns = (NT - ti + SW - 1) >> 2; }
    const int st = rem;                       // strip index within row ti
    const int tjs = ti + st * SW;             // first tile of strip
    const int WT = min(SW, NT - tjs);         // tiles in this strip
    const int NJ = 2 * WT;                    // 64-col iterations

    const int rowbase = ti * TI + w * 32;
    const int cstart = tjs * TI;

    // strip labels (WT*128 <= 512)
    for (int x = tid; x < WT * TI; x += 256) Lall[x] = labels[cstart + x];

    // A fragments: afrag[rs][kc] = 16B of row (rowbase+rs*16+l16), chunk (kc*4+quad)
    bf16x8 afrag[2][8];
    #pragma unroll
    for (int rs = 0; rs < 2; rs++)
        #pragma unroll
        for (int kc = 0; kc < 8; kc++) {
            const size_t u = (size_t)(kc * 4 + quad) * NB + (rowbase + rs * 16 + l16);
            afrag[rs][kc] = *(const bf16x8*)(Xbt + u * 8);
        }

    // row labels packed 4x8-bit per rs (labels < 128 fit in a byte)
    unsigned int lpack[2];
    #pragma unroll
    for (int rs = 0; rs < 2; rs++) {
        unsigned int p = 0;
        #pragma unroll
        for (int r = 0; r < 4; r++)
            p |= ((unsigned int)labels[rowbase + rs * 16 + quad * 4 + r] & 0xffu)
                 << (8 * r);
        lpack[rs] = p;
    }

    float minK[2][4], maxK[2][4];
    #pragma unroll
    for (int rs = 0; rs < 2; rs++)
        #pragma unroll
        for (int r = 0; r < 4; r++) { minK[rs][r] = 1e30f; maxK[rs][r] = -1e30f; }

    auto stage = [&](int jj) {
        const int jbase = cstart + jj * BJ;
        #pragma unroll
        for (int s_ = 0; s_ < 8; s_++) {
            const int rg = w * 8 + s_;                // 32 regions over 4 waves
            const int kc = rg >> 2, nfi = rg & 3;
            const size_t u = (size_t)(kc * 4 + quad) * NB + (jbase + nfi * 16 + l16);
            load_lds16(Xbt + u * 8, Bt + rg * 512);
        }
    };

    stage(0);
    __syncthreads();   // vmcnt drained: Bt(0) + Lall ready

    #pragma unroll 1
    for (int jj = 0; jj < NJ; jj++) {
        #pragma unroll
        for (int nf = 0; nf < 4; nf++) {
            const int flc = Lall[jj * BJ + nf * 16 + l16];
            f32x4 acc[2];
            #pragma unroll
            for (int rs = 0; rs < 2; rs++) acc[rs] = (f32x4){0.f, 0.f, 0.f, 0.f};
            #pragma unroll
            for (int kc = 0; kc < 8; kc++) {
                const bf16x8 b = *(const bf16x8*)(Bt + (kc * 4 + nf) * 512 + lane * 8);
                #pragma unroll
                for (int rs = 0; rs < 2; rs++)
                    acc[rs] = __builtin_amdgcn_mfma_f32_16x16x32_bf16(
                        afrag[rs][kc], b, acc[rs], 0, 0, 0);
            }
            float cP = 1e30f, cN = -1e30f;
            #pragma unroll
            for (int rs = 0; rs < 2; rs++)
                #pragma unroll
                for (int r = 0; r < 4; r++) {
                    const int lr = (int)((lpack[rs] >> (8 * r)) & 0xffu);
                    const float key = acc[rs][r] + ((lr != flc) ? 8.0f : 0.0f);
                    minK[rs][r] = fminf(minK[rs][r], key);   // row-direction
                    maxK[rs][r] = fmaxf(maxK[rs][r], key);
                    cP = fminf(cP, key);                     // col-direction
                    cN = fmaxf(cN, key);
                }
            // col-dir: combine the 4 quads (lanes sharing l16) -> min over 32 rows
            cP = fminf(cP, __shfl_xor(cP, 16, 64));
            cP = fminf(cP, __shfl_xor(cP, 32, 64));
            cN = fmaxf(cN, __shfl_xor(cN, 16, 64));
            cN = fmaxf(cN, __shfl_xor(cN, 32, 64));
            if (quad == 0) {
                colMn[w][nf * 16 + l16] = cP;
                colMx[w][nf * 16 + l16] = cN;
            }
        }
        __syncthreads();            // Bt reads + colMn/colMx writes done
        if (jj + 1 < NJ) stage(jj + 1);
        // flush col-direction partials for this jj: PLAIN stores, slot ti
        if (tid < BJ) {
            float m = colMn[0][tid];
            #pragma unroll
            for (int ww = 1; ww < 4; ww++) m = fminf(m, colMn[ww][tid]);
            posP[(size_t)ti * NB + cstart + jj * BJ + tid] = m;
        } else if (tid < 2 * BJ) {
            const int c = tid - BJ;
            float M = colMx[0][c];
            #pragma unroll
            for (int ww = 1; ww < 4; ww++) M = fmaxf(M, colMx[ww][c]);
            negP[(size_t)ti * NB + cstart + jj * BJ + c] = M;
        }
        __syncthreads();            // staged Bt landed (vmcnt 0)
    }

    // row-direction (accumulated over the whole strip): reduce across the 16
    // lanes sharing each row; PLAIN store into row-slot 64+st.
    #pragma unroll
    for (int rs = 0; rs < 2; rs++)
        #pragma unroll
        for (int r = 0; r < 4; r++) {
            float p = minK[rs][r], n = maxK[rs][r];
            #pragma unroll
            for (int m = 1; m <= 8; m <<= 1) {
                p = fminf(p, __shfl_xor(p, m, 64));
                n = fmaxf(n, __shfl_xor(n, m, 64));
            }
            if (l16 == 0) {
                const int row = rowbase + rs * 16 + quad * 4 + r;
                posP[(size_t)(64 + st) * NB + row] = p;
                negP[(size_t)(64 + st) * NB + row] = n;
            }
        }
}

// ---------------- Kernel 3: reduce valid slots, hinge, finalize -------------
// Index i (tile t=i/128) has valid col-slots u=0..t and row-slots
// 64..64+ceil((64-t)/4)-1; all other slots were never written.
__global__ __launch_bounds__(256) void finish_kernel(
    const float* __restrict__ posP, const float* __restrict__ negP,
    float* accum, int* done, float* __restrict__ out) {
    const int i = blockIdx.x * 256 + threadIdx.x;
    const int t = i >> 7;
    float p = 1e30f, n = -1e30f;
    for (int u = 0; u <= t; u++) {
        p = fminf(p, posP[(size_t)u * NB + i]);
        n = fmaxf(n, negP[(size_t)u * NB + i]);
    }
    const int nst = (NT - t + SW - 1) >> 2;
    for (int s2 = 0; s2 < nst; s2++) {
        p = fminf(p, posP[(size_t)(64 + s2) * NB + i]);
        n = fmaxf(n, negP[(size_t)(64 + s2) * NB + i]);
    }
    // p < 4: some positive existed; n > 4: some negative existed (key = s+8)
    const bool valid = (p < 4.0f) && (n > 4.0f);
    const float pos_d = fmaxf(1.0f - p, 0.0f);
    const float neg_d = fmaxf(1.0f - (n - 8.0f), 0.0f);
    float per = valid ? fmaxf(pos_d - neg_d + 1.0f, 0.0f) : 0.0f;
    float cnt = valid ? 1.0f : 0.0f;
    #pragma unroll
    for (int off = 32; off > 0; off >>= 1) {
        per += __shfl_down(per, off, 64);
        cnt += __shfl_down(cnt, off, 64);
    }
    __shared__ float sp[4], sc[4];
    const int wv = threadIdx.x >> 6, ln = threadIdx.x & 63;
    if (ln == 0) { sp[wv] = per; sc[wv] = cnt; }
    __syncthreads();
    if (threadIdx.x == 0) {
        atomicAdd(&accum[0], sp[0] + sp[1] + sp[2] + sp[3]);
        atomicAdd(&accum[1], sc[0] + sc[1] + sc[2] + sc[3]);
        __threadfence();
        const int old = atomicAdd(done, 1);
        if (old == (int)gridDim.x - 1) {
            const float s = __hip_atomic_load(&accum[0], __ATOMIC_RELAXED,
                                              __HIP_MEMORY_SCOPE_AGENT);
            const float c = __hip_atomic_load(&accum[1], __ATOMIC_RELAXED,
                                              __HIP_MEMORY_SCOPE_AGENT);
            out[0] = (c > 0.f) ? s / fmaxf(c, 1.f) : 0.f;
        }
    }
}

// ---------------- launcher --------------------------------------------------
extern "C" void kernel_launch(void* const* d_in, const int* in_sizes, int n_in,
                              void* d_out, int out_size, void* d_ws, size_t ws_size,
                              hipStream_t stream) {
    const float* X = (const float*)d_in[0];
    const int* labels = (const int*)d_in[1];
    float* out = (float*)d_out;

    char* ws = (char*)d_ws;
    unsigned short* Xbt = (unsigned short*)ws;                    // 4 MB
    float* posP = (float*)(ws + (size_t)4 * 1024 * 1024);         // 2.625 MB
    float* negP = posP + (size_t)NSLOT * NB;                      // 2.625 MB
    float* accum = negP + (size_t)NSLOT * NB;                     // 8 B
    int* done = (int*)(accum + 2);                                // 4 B

    norm_kernel<<<NB / 32, 256, 0, stream>>>(X, Xbt, accum, done);
    mine_kernel<<<NBLK, 256, 0, stream>>>(
        (const unsigned short*)Xbt, labels, posP, negP);
    finish_kernel<<<NB / 256, 256, 0, stream>>>(posP, negP, accum, done, out);
}

// Round 13
// 99.362 us; speedup vs baseline: 1.1598x; 1.1512x over previous
//
#include <hip/hip_runtime.h>
#include <hip/hip_bf16.h>

// TripletLoss batch-hard mining, B=8192, D=256.
// R14 = R6 verbatim (session best: 97.05 us, passed, absmax 0).
// Structure: 3 kernels. norm: register-resident row normalize -> bf16
// chunk-major. mine: full-grid Gram, 8-wave/512-thr blocks, wave owns 32
// rows (afrag[2][8] = 64 VGPR, lb(512,4) -> 4 waves/SIMD, 16 waves/CU),
// B-tile double-buffered in LDS with stage(jt+1)-before-compute + single
// barrier per tile; label-encoded mining key. finish: 16-slot reduce +
// hinge + done-counter finalize.
// Session evidence: symmetric-Gram variants (R7-R13) never beat this
// (spills / occupancy quantization / atomics); dbuf-beyond-this null (R4);
// mine runs ~870 TF = the plain-HIP 2-barrier structural ceiling.

constexpr int NB = 8192;
constexpr int ND = 256;
constexpr int BI = 256;               // rows per block (8 waves x 32 rows)
constexpr int BJ = 64;                // cols per iteration
constexpr int JSPLIT = 16;            // grid.y
constexpr int JRANGE = NB / JSPLIT;   // 512
constexpr int NITER = JRANGE / BJ;    // 8

typedef __attribute__((ext_vector_type(8))) short bf16x8;
typedef __attribute__((ext_vector_type(4))) float f32x4;

typedef __attribute__((address_space(3))) unsigned int lds_u32;
typedef __attribute__((address_space(1))) const unsigned int g_u32;

__device__ inline void load_lds16(const unsigned short* g, unsigned short* l) {
    __builtin_amdgcn_global_load_lds((g_u32*)g, (lds_u32*)l, 16, 0, 0);
}

__device__ inline unsigned short f2bf(float v) {
    __hip_bfloat16 b = __float2bfloat16(v);
    return *reinterpret_cast<unsigned short*>(&b);
}

// ---------------- Kernel 1: normalize rows -> bf16, CHUNK-MAJOR ------------
// Register-resident: 8 threads/row, 32 floats/thread, butterfly row reduce.
__global__ __launch_bounds__(256) void norm_kernel(const float* __restrict__ X,
                                                   unsigned short* __restrict__ Xbt,
                                                   float* accum, int* done) {
    const int t = threadIdx.x;
    const int rb = blockIdx.x * 32;
    const int r = t >> 3, e = t & 7;
    if (blockIdx.x == 0 && t == 0) { accum[0] = 0.f; accum[1] = 0.f; *done = 0; }

    const float4* src = (const float4*)(X + (size_t)(rb + r) * ND + e * 32);
    float4 v[8];
    #pragma unroll
    for (int k = 0; k < 8; k++) v[k] = src[k];

    float s = 0.f;
    #pragma unroll
    for (int k = 0; k < 8; k++) {
        s += v[k].x * v[k].x; s += v[k].y * v[k].y;
        s += v[k].z * v[k].z; s += v[k].w * v[k].w;
    }
    #pragma unroll
    for (int m = 1; m <= 4; m <<= 1) s += __shfl_xor(s, m, 64);
    const float sc = 1.0f / fmaxf(sqrtf(s), 1e-12f);

    #pragma unroll
    for (int k = 0; k < 4; k++) {
        const float* f = (const float*)&v[2 * k];
        unsigned short tmp[8];
        #pragma unroll
        for (int q = 0; q < 8; q++) tmp[q] = f2bf(f[q] * sc);
        *(bf16x8*)(Xbt + ((size_t)(e * 4 + k) * NB + rb + r) * 8) = *(bf16x8*)tmp;
    }
}

// ---------------- Kernel 2: Gram + hard mining ------------------------------
// 8 waves/block; wave owns 32 rows (2 x 16), K=256 of A in registers (64 VGPR).
// B-tile (64 cols) staged in LDS in READ-ORDER: region rg = kc*4+nf holds,
// at lane L*16B:  B[col = nf*16 + (L&15)][kchunk = kc*4 + (L>>4)]
// => every ds_read_b128 is lane-sequential (conflict-free).
// Mining key: key = s + 8*min(|lrow-lcol|,1); min(key)=hardest-pos sim,
// max(key)=8+hardest-neg sim. Diagonal (s~1) can never win the pos-min.
__global__ __launch_bounds__(512, 4) void mine_kernel(
    const unsigned short* __restrict__ Xbt, const int* __restrict__ labels,
    float* __restrict__ posP, float* __restrict__ negP) {
    __shared__ __align__(16) unsigned short Bt[2][32 * 512];  // 64 KB dbuf
    __shared__ float Lall[JRANGE];                            // 2 KB labels

    const int tid = threadIdx.x;
    const int w = tid >> 6;           // 0..7
    const int lane = tid & 63;
    const int quad = lane >> 4;
    const int l16 = lane & 15;

    const int rowbase = blockIdx.x * BI + w * 32;
    const int jstart = blockIdx.y * JRANGE;

    // one-time preload of all 512 column labels for this split
    Lall[tid] = (float)labels[jstart + tid];

    // A fragments: afrag[rs][kc] = 16B of row (rowbase+rs*16+l16), chunk (kc*4+quad)
    bf16x8 afrag[2][8];
    #pragma unroll
    for (int rs = 0; rs < 2; rs++)
        #pragma unroll
        for (int kc = 0; kc < 8; kc++) {
            const size_t u = (size_t)(kc * 4 + quad) * NB + (rowbase + rs * 16 + l16);
            afrag[rs][kc] = *(const bf16x8*)(Xbt + u * 8);
        }

    float flr[2][4];
    float minK[2][4], maxK[2][4];
    #pragma unroll
    for (int rs = 0; rs < 2; rs++)
        #pragma unroll
        for (int r = 0; r < 4; r++) {
            flr[rs][r] = (float)labels[rowbase + rs * 16 + quad * 4 + r];
            minK[rs][r] = 1e30f;
            maxK[rs][r] = -1e30f;
        }

    auto stage = [&](int buf, int jt) {
        const int jbase = jstart + jt * BJ;
        #pragma unroll
        for (int s = 0; s < 4; s++) {
            const int rg = w * 4 + s;                 // 32 regions over 8 waves
            const int kc = rg >> 2, nfi = rg & 3;
            const size_t u = (size_t)(kc * 4 + quad) * NB + (jbase + nfi * 16 + l16);
            load_lds16(Xbt + u * 8, &Bt[buf][rg * 512]);
        }
    };

    stage(0, 0);
    __syncthreads();   // Bt[0], Lall ready

    for (int jt = 0; jt < NITER; jt++) {
        const int cur = jt & 1;
        if (jt + 1 < NITER) stage(cur ^ 1, jt + 1);   // async; lands under MFMA

        #pragma unroll
        for (int nf = 0; nf < 4; nf++) {
            const float flc = Lall[jt * BJ + nf * 16 + l16];
            f32x4 acc[2];
            #pragma unroll
            for (int rs = 0; rs < 2; rs++) acc[rs] = (f32x4){0.f, 0.f, 0.f, 0.f};
            #pragma unroll
            for (int kc = 0; kc < 8; kc++) {
                const bf16x8 b = *(const bf16x8*)(&Bt[cur][(kc * 4 + nf) * 512 + lane * 8]);
                #pragma unroll
                for (int rs = 0; rs < 2; rs++)
                    acc[rs] = __builtin_amdgcn_mfma_f32_16x16x32_bf16(
                        afrag[rs][kc], b, acc[rs], 0, 0, 0);
            }
            #pragma unroll
            for (int rs = 0; rs < 2; rs++)
                #pragma unroll
                for (int r = 0; r < 4; r++) {
                    const float d = flr[rs][r] - flc;
                    const float uu = fminf(fabsf(d), 1.0f);
                    const float key = fmaf(uu, 8.0f, acc[rs][r]);
                    minK[rs][r] = fminf(minK[rs][r], key);
                    maxK[rs][r] = fmaxf(maxK[rs][r], key);
                }
        }
        __syncthreads();  // stage(jt+1) landed; Bt[cur] free for overwrite
    }

    // reduce across the 16 lanes (bits 0..3) sharing each row
    #pragma unroll
    for (int rs = 0; rs < 2; rs++)
        #pragma unroll
        for (int r = 0; r < 4; r++) {
            float p = minK[rs][r], n = maxK[rs][r];
            #pragma unroll
            for (int m = 1; m <= 8; m <<= 1) {
                p = fminf(p, __shfl_xor(p, m, 64));
                n = fmaxf(n, __shfl_xor(n, m, 64));
            }
            if (l16 == 0) {
                const int row = rowbase + rs * 16 + quad * 4 + r;
                posP[blockIdx.y * NB + row] = p;
                negP[blockIdx.y * NB + row] = n;
            }
        }
}

// ---------------- Kernel 3: combine splits, hinge, global reduce, finalize --
__global__ __launch_bounds__(256) void finish_kernel(
    const float* __restrict__ posP, const float* __restrict__ negP,
    float* accum, int* done, float* __restrict__ out) {
    const int i = blockIdx.x * 256 + threadIdx.x;
    float p = 1e30f, n = -1e30f;
    #pragma unroll
    for (int s = 0; s < JSPLIT; s++) {
        p = fminf(p, posP[s * NB + i]);
        n = fmaxf(n, negP[s * NB + i]);
    }
    // p < 4: some positive existed; n > 4: some negative existed (key = s+8)
    const bool valid = (p < 4.0f) && (n > 4.0f);
    const float pos_d = fmaxf(1.0f - p, 0.0f);
    const float neg_d = fmaxf(1.0f - (n - 8.0f), 0.0f);
    float per = valid ? fmaxf(pos_d - neg_d + 1.0f, 0.0f) : 0.0f;
    float cnt = valid ? 1.0f : 0.0f;
    #pragma unroll
    for (int off = 32; off > 0; off >>= 1) {
        per += __shfl_down(per, off, 64);
        cnt += __shfl_down(cnt, off, 64);
    }
    __shared__ float sp[4], sc[4];
    const int wv = threadIdx.x >> 6, ln = threadIdx.x & 63;
    if (ln == 0) { sp[wv] = per; sc[wv] = cnt; }
    __syncthreads();
    if (threadIdx.x == 0) {
        atomicAdd(&accum[0], sp[0] + sp[1] + sp[2] + sp[3]);
        atomicAdd(&accum[1], sc[0] + sc[1] + sc[2] + sc[3]);
        __threadfence();
        const int old = atomicAdd(done, 1);
        if (old == (int)gridDim.x - 1) {
            const float s = __hip_atomic_load(&accum[0], __ATOMIC_RELAXED,
                                              __HIP_MEMORY_SCOPE_AGENT);
            const float c = __hip_atomic_load(&accum[1], __ATOMIC_RELAXED,
                                              __HIP_MEMORY_SCOPE_AGENT);
            out[0] = (c > 0.f) ? s / fmaxf(c, 1.f) : 0.f;
        }
    }
}

// ---------------- launcher --------------------------------------------------
extern "C" void kernel_launch(void* const* d_in, const int* in_sizes, int n_in,
                              void* d_out, int out_size, void* d_ws, size_t ws_size,
                              hipStream_t stream) {
    const float* X = (const float*)d_in[0];
    const int* labels = (const int*)d_in[1];
    float* out = (float*)d_out;

    char* ws = (char*)d_ws;
    unsigned short* Xbt = (unsigned short*)ws;                    // 4 MB
    float* posP = (float*)(ws + (size_t)4 * 1024 * 1024);         // 512 KB
    float* negP = posP + JSPLIT * NB;                             // 512 KB
    float* accum = negP + JSPLIT * NB;                            // 8 B
    int* done = (int*)(accum + 2);                                // 4 B

    norm_kernel<<<NB / 32, 256, 0, stream>>>(X, Xbt, accum, done);
    mine_kernel<<<dim3(NB / BI, JSPLIT), 512, 0, stream>>>(
        (const unsigned short*)Xbt, labels, posP, negP);
    finish_kernel<<<NB / 256, 256, 0, stream>>>(posP, negP, accum, done, out);
}